// Round 1
// baseline (44.421 us; speedup 1.0000x reference)
//
#include <hip/hip_runtime.h>

#define TPB 1024
#define EPT 32
#define TILE (TPB * EPT)
#define WAVE 64
#define NWAVES (TPB / WAVE)

__global__ __launch_bounds__(TPB, 1)
void stage2_scan_kernel(const float* __restrict__ tt,
                        const float* __restrict__ p,
                        const float* __restrict__ h_raw,
                        float* __restrict__ out,
                        int Nt)
{
    const int row  = blockIdx.x;
    const int tid  = threadIdx.x;
    const int lane = tid & (WAVE - 1);
    const int wid  = tid >> 6;

    __shared__ float sWtot[NWAVES];
    __shared__ float sC[NWAVES + 1];   // per-wave exclusive carry + next-tile carry

    // Per-row parameters (broadcast loads)
    const float E1  = h_raw[row * 3 + 0];
    const float E2  = h_raw[row * 3 + 1];
    const float eta = h_raw[row * 3 + 2];
    const float alpha = (E1 * E2) / ((E1 + E2) * eta);
    const float A  = 0.206756f / (E1 + E2);
    const float D  = 0.206756f * E1 / (E2 * (E1 + E2));
    const float AD = A + D;
    const float dtm = (tt[Nt - 1] - tt[0]) / (float)(Nt - 1);
    const float d   = expf(-alpha * dtm);     // per-step decay (accurate expf!)

    // chunk ratio r = d^EPT (5 squarings), computed per thread
    float r = d;
    #pragma unroll
    for (int i = 0; i < 5; ++i) r = r * r;    // d^32

    const long long rowbase = (long long)row * (long long)Nt;
    float c_prev = 0.0f;

    for (int t0 = 0; t0 < Nt; t0 += TILE) {
        const int base = t0 + tid * EPT;
        const bool full = (base + EPT <= Nt);

        // ---- load this thread's chunk into registers (p read exactly once) ----
        float pv[EPT];
        if (full) {
            const float4* p4 = reinterpret_cast<const float4*>(p + rowbase + base);
            #pragma unroll
            for (int i = 0; i < EPT / 4; ++i) {
                float4 v = p4[i];
                pv[4*i+0] = v.x; pv[4*i+1] = v.y; pv[4*i+2] = v.z; pv[4*i+3] = v.w;
            }
        } else {
            #pragma unroll
            for (int i = 0; i < EPT; ++i)
                pv[i] = (base + i < Nt) ? p[rowbase + base + i] : 0.0f;
        }
        float pprev = 0.0f;
        if (base >= 1 && base <= Nt) pprev = p[rowbase + base - 1];

        // ---- pass 1: local scan with zero carry -> chunk total L ----
        float s = 0.0f;
        {
            float pp = pprev;
            #pragma unroll
            for (int i = 0; i < EPT; ++i) {
                if (full || (base + i < Nt)) {
                    float dp = pv[i] - pp;
                    s = fmaf(d, s, dp);
                    pp = pv[i];
                }
            }
        }
        float L = s;

        // ---- wave-level inclusive scan of L with ratio r (Kogge-Stone, shuffles) ----
        float x = L;
        float m = r;
        #pragma unroll
        for (int k = 1; k < WAVE; k <<= 1) {
            float y = __shfl_up(x, k);
            if (lane >= k) x = fmaf(m, y, x);
            m = m * m;
        }
        const float R = m;                 // r^64 = d^(64*EPT)
        float wave_excl = __shfl_up(x, 1);
        if (lane == 0) wave_excl = 0.0f;
        if (lane == WAVE - 1) sWtot[wid] = x;
        __syncthreads();

        // ---- cross-wave scan (wave 0, 16 values, ratio R) ----
        if (wid == 0 && lane < NWAVES) {
            float xi = sWtot[lane];
            float mm = R;
            #pragma unroll
            for (int k = 1; k < NWAVES; k <<= 1) {
                float y = __shfl_up(xi, k);
                if (lane >= k) xi = fmaf(mm, y, xi);
                mm = mm * mm;
            }
            float excl = __shfl_up(xi, 1);
            if (lane == 0) excl = 0.0f;
            // fold in previous-tile carry: + c_prev * R^lane
            float Rl = 1.0f;
            {
                float b = R;
                #pragma unroll
                for (int bit = 0; bit < 4; ++bit) {
                    if (lane & (1 << bit)) Rl *= b;
                    b *= b;
                }
            }
            sC[lane] = fmaf(c_prev, Rl, excl);
            if (lane == NWAVES - 1) sC[NWAVES] = fmaf(c_prev, Rl * R, xi);
        }
        __syncthreads();

        const float Cw     = sC[wid];
        const float c_next = sC[NWAVES];

        // r^lane via binary exponentiation
        float rl = 1.0f;
        {
            float b = r;
            #pragma unroll
            for (int bit = 0; bit < 6; ++bit) {
                if (lane & (1 << bit)) rl *= b;
                b *= b;
            }
        }
        const float carry = fmaf(rl, Cw, wave_excl);

        // ---- pass 2: recompute recurrence seeded with carry; write omega ----
        {
            float s2 = carry;
            float pp = pprev;
            if (full) {
                float4* o4 = reinterpret_cast<float4*>(out + rowbase + base);
                #pragma unroll
                for (int g = 0; g < EPT / 4; ++g) {
                    float4 o;
                    float dp, pvv;
                    pvv = pv[4*g+0]; dp = pvv - pp; s2 = fmaf(d, s2, dp); pp = pvv;
                    o.x = fmaf(AD, pvv, -(D * s2));
                    pvv = pv[4*g+1]; dp = pvv - pp; s2 = fmaf(d, s2, dp); pp = pvv;
                    o.y = fmaf(AD, pvv, -(D * s2));
                    pvv = pv[4*g+2]; dp = pvv - pp; s2 = fmaf(d, s2, dp); pp = pvv;
                    o.z = fmaf(AD, pvv, -(D * s2));
                    pvv = pv[4*g+3]; dp = pvv - pp; s2 = fmaf(d, s2, dp); pp = pvv;
                    o.w = fmaf(AD, pvv, -(D * s2));
                    o4[g] = o;
                }
            } else {
                #pragma unroll
                for (int i = 0; i < EPT; ++i) {
                    if (base + i < Nt) {
                        float dp = pv[i] - pp;
                        s2 = fmaf(d, s2, dp);
                        pp = pv[i];
                        out[rowbase + base + i] = fmaf(AD, pv[i], -(D * s2));
                    }
                }
            }
        }

        c_prev = c_next;
        __syncthreads();   // protect sWtot/sC before next tile
    }
}

extern "C" void kernel_launch(void* const* d_in, const int* in_sizes, int n_in,
                              void* d_out, int out_size, void* d_ws, size_t ws_size,
                              hipStream_t stream)
{
    // inputs: 0=h (unused), 1=t (Nt), 2=p (B*Nt), 3=h_raw (B*3)
    const float* tt    = (const float*)d_in[1];
    const float* p     = (const float*)d_in[2];
    const float* h_raw = (const float*)d_in[3];
    float* out = (float*)d_out;

    const int Nt = in_sizes[1];
    const int B  = in_sizes[2] / Nt;

    stage2_scan_kernel<<<B, TPB, 0, stream>>>(tt, p, h_raw, out, Nt);
}